// Round 10
// baseline (489.787 us; speedup 1.0000x reference)
//
#include <hip/hip_runtime.h>
#include <hip/hip_bf16.h>

#define N_NODES 100000
#define N_USERS 200000
#define N_ITEMS 200000
#define KNEI 24
#define E 64
#define F 128

typedef __attribute__((ext_vector_type(8))) short bf16x8;
typedef __attribute__((ext_vector_type(4))) float f32x4;

// ---- workspace layout (bytes) ----
// comb   bf16 [N_ITEMS][128]: off 0          size 51,200,000  (row = [i_att(64) | i_proj(64)])
// q_att  bf16 [N_NODES][64] : off 51,200,000 size 12,800,000
// winner int  [N_USERS]     : off 64,000,000 size    800,000
// W'     f32  [128][64]     : off 64,800,000 size     32,768
// b'     f32  [64]          : off 64,832,768 size        256
// B2img  bf16 [8][64][8]    : off 64,833,024 size      8,192   (aW2 B-frag image)
// bw     f32  [64][8]       : off 64,841,216 size      2,048   (ab2|aW3 splat image)

__device__ inline float bf2f(short s) {
    unsigned u = ((unsigned)(unsigned short)s) << 16;
    return __uint_as_float(u);
}
__device__ inline short f2bf(float f) {
    __hip_bfloat16 h = __float2bfloat16(f);
    return *reinterpret_cast<short*>(&h);
}
__device__ inline bf16x8 pack8(float4 a, float4 b) {
    bf16x8 r;
    r[0] = f2bf(a.x); r[1] = f2bf(a.y); r[2] = f2bf(a.z); r[3] = f2bf(a.w);
    r[4] = f2bf(b.x); r[5] = f2bf(b.y); r[6] = f2bf(b.z); r[7] = f2bf(b.w);
    return r;
}

// ---- fuse: W' = iW@aW1a ; b' = ib@aW1a + ab1 ; aW2 frag image ; ab2/aW3 splat image ----
__global__ __launch_bounds__(256) void k_fuse(const float* __restrict__ iW,
                                              const float* __restrict__ aW1,
                                              const float* __restrict__ ib,
                                              const float* __restrict__ ab1,
                                              const float* __restrict__ aW2,
                                              const float* __restrict__ ab2,
                                              const float* __restrict__ aW3,
                                              float* __restrict__ Wp,
                                              float* __restrict__ bp,
                                              bf16x8* __restrict__ B2img,
                                              float* __restrict__ bw) {
    int g = blockIdx.x * 256 + threadIdx.x;
    if (g < 8192) {
        int f = g >> 6, c = g & 63;
        float s = 0.f;
        for (int j = 0; j < 64; j++) s = fmaf(iW[f * 64 + j], aW1[j * 64 + c], s);
        Wp[g] = s;
        if (g < 64) {
            float b = ab1[g];
            for (int j = 0; j < 64; j++) b = fmaf(ib[j], aW1[j * 64 + g], b);
            bp[g] = b;
        }
    } else if (g < 8192 + 512) {
        int h = g - 8192;
        int f = h >> 6, l = h & 63;
        int s = f >> 2, u = f & 3;
        int lo = l & 15, hi = l >> 4;
        bf16x8 b;
        #pragma unroll
        for (int e = 0; e < 8; e++)
            b[e] = f2bf(aW2[(size_t)(32 * s + 8 * hi + e) * 64 + 16 * u + lo]);
        B2img[h] = b;
        if (f == 0) {
            #pragma unroll
            for (int uu = 0; uu < 4; uu++) {
                bw[l * 8 + uu]     = ab2[16 * uu + lo];
                bw[l * 8 + 4 + uu] = aW3[16 * uu + lo];
            }
        }
    }
}

// MFMA lane mappings (correctness-proven rounds 2-9):
//   A frag 16x16x32: lane l -> row = l&15, k = 8*(l>>4)+e
//   B frag:          lane l -> col = l&15, k = 8*(l>>4)+e
//   C/D:             lane l -> col = l&15, row = 4*(l>>4)+reg

// ---- per-item: comb row = [i_att | i_proj] (one A pass, interleaved store) ----
__global__ __launch_bounds__(256, 2) void k_item(const float* __restrict__ iwt,
                                                 const float* __restrict__ iW,
                                                 const float* __restrict__ ib,
                                                 const float* __restrict__ Wp,
                                                 const float* __restrict__ bp,
                                                 __hip_bfloat16* __restrict__ comb) {
    const int wave = threadIdx.x >> 6, lane = threadIdx.x & 63;
    const int lo = lane & 15, hi = lane >> 4;

    bf16x8 B1[4][4], B2[4][4];
    #pragma unroll
    for (int s = 0; s < 4; s++) {
        #pragma unroll
        for (int u = 0; u < 4; u++) {
            bf16x8 b1, b2;
            #pragma unroll
            for (int e = 0; e < 8; e++) {
                int k = 32 * s + 8 * hi + e;
                b1[e] = f2bf(iW[k * 64 + 16 * u + lo]);
                b2[e] = f2bf(Wp[k * 64 + 16 * u + lo]);
            }
            B1[s][u] = b1; B2[s][u] = b2;
        }
    }
    float bi[4], ba[4];
    #pragma unroll
    for (int u = 0; u < 4; u++) { bi[u] = ib[16 * u + lo]; ba[u] = bp[16 * u + lo]; }

    const int wid = blockIdx.x * 4 + wave;
    for (int t = wid; t < N_ITEMS / 16; t += 1024 * 4) {
        int r0 = t * 16;
        const float4* Ap = reinterpret_cast<const float4*>(iwt + (size_t)(r0 + lo) * F);
        bf16x8 A[4];
        #pragma unroll
        for (int s = 0; s < 4; s++)
            A[s] = pack8(Ap[8 * s + 2 * hi], Ap[8 * s + 2 * hi + 1]);
        f32x4 acc1[4], acc2[4];
        #pragma unroll
        for (int u = 0; u < 4; u++) {
            acc1[u] = (f32x4){bi[u], bi[u], bi[u], bi[u]};
            acc2[u] = (f32x4){ba[u], ba[u], ba[u], ba[u]};
        }
        #pragma unroll
        for (int s = 0; s < 4; s++) {
            #pragma unroll
            for (int u = 0; u < 4; u++) {
                acc1[u] = __builtin_amdgcn_mfma_f32_16x16x32_bf16(A[s], B1[s][u], acc1[u], 0, 0, 0);
                acc2[u] = __builtin_amdgcn_mfma_f32_16x16x32_bf16(A[s], B2[s][u], acc2[u], 0, 0, 0);
            }
        }
        #pragma unroll
        for (int u = 0; u < 4; u++) {
            #pragma unroll
            for (int reg = 0; reg < 4; reg++) {
                size_t off = (size_t)(r0 + 4 * hi + reg) * 128 + 16 * u + lo;
                comb[off]      = __float2bfloat16(acc2[u][reg]);   // i_att half
                comb[off + 64] = __float2bfloat16(acc1[u][reg]);   // i_proj half
            }
        }
    }
}

// ---- per-node pass 1: nodes_fea = u_weight[nodes]@uW + ub (f32 out) + winner ----
__global__ __launch_bounds__(256, 2) void k_node1(const int* __restrict__ nodes,
                                                  const float* __restrict__ uwt,
                                                  const float* __restrict__ uW,
                                                  const float* __restrict__ ub,
                                                  float* __restrict__ out_nf,
                                                  int* __restrict__ winner) {
    const int wave = threadIdx.x >> 6, lane = threadIdx.x & 63;
    const int lo = lane & 15, hi = lane >> 4;

    bf16x8 B[4][4];
    #pragma unroll
    for (int s = 0; s < 4; s++) {
        #pragma unroll
        for (int u = 0; u < 4; u++) {
            bf16x8 b;
            #pragma unroll
            for (int e = 0; e < 8; e++) {
                int k = 32 * s + 8 * hi + e;
                b[e] = f2bf(uW[k * 64 + 16 * u + lo]);
            }
            B[s][u] = b;
        }
    }
    float bu[4];
    #pragma unroll
    for (int u = 0; u < 4; u++) bu[u] = ub[16 * u + lo];

    const int wid = blockIdx.x * 4 + wave;
    for (int t = wid; t < N_NODES / 16; t += 512 * 4) {
        int r0 = t * 16;
        int n = r0 + lo;
        int un = nodes[n];
        if (hi == 0) atomicMax(&winner[un], n);
        const float4* Ap = reinterpret_cast<const float4*>(uwt + (size_t)un * F);
        bf16x8 A[4];
        #pragma unroll
        for (int s = 0; s < 4; s++)
            A[s] = pack8(Ap[8 * s + 2 * hi], Ap[8 * s + 2 * hi + 1]);
        f32x4 acc[4];
        #pragma unroll
        for (int u = 0; u < 4; u++) acc[u] = (f32x4){bu[u], bu[u], bu[u], bu[u]};
        #pragma unroll
        for (int s = 0; s < 4; s++) {
            #pragma unroll
            for (int u = 0; u < 4; u++)
                acc[u] = __builtin_amdgcn_mfma_f32_16x16x32_bf16(A[s], B[s][u], acc[u], 0, 0, 0);
        }
        #pragma unroll
        for (int u = 0; u < 4; u++) {
            #pragma unroll
            for (int reg = 0; reg < 4; reg++)
                out_nf[(size_t)(r0 + 4 * hi + reg) * E + 16 * u + lo] = acc[u][reg];
        }
    }
}

// ---- per-node pass 2: q_att = (nodes_fea + n_feature) @ aW1[64:] (bf16 ws) ----
__global__ __launch_bounds__(256, 2) void k_node2(const float* __restrict__ out_nf,
                                                  const float* __restrict__ nfeat,
                                                  const float* __restrict__ aW1,
                                                  __hip_bfloat16* __restrict__ qatt) {
    const int wave = threadIdx.x >> 6, lane = threadIdx.x & 63;
    const int lo = lane & 15, hi = lane >> 4;

    bf16x8 B[2][4];
    #pragma unroll
    for (int s = 0; s < 2; s++) {
        #pragma unroll
        for (int u = 0; u < 4; u++) {
            bf16x8 b;
            #pragma unroll
            for (int e = 0; e < 8; e++) {
                int k = 32 * s + 8 * hi + e;
                b[e] = f2bf(aW1[(size_t)(E + k) * 64 + 16 * u + lo]);
            }
            B[s][u] = b;
        }
    }

    const int wid = blockIdx.x * 4 + wave;
    for (int t = wid; t < N_NODES / 16; t += 512 * 4) {
        int r0 = t * 16;
        const float4* Op = reinterpret_cast<const float4*>(out_nf + (size_t)(r0 + lo) * E);
        const float4* Np = reinterpret_cast<const float4*>(nfeat + (size_t)(r0 + lo) * E);
        bf16x8 A[2];
        #pragma unroll
        for (int s = 0; s < 2; s++) {
            float4 o0 = Op[8 * s + 2 * hi], o1 = Op[8 * s + 2 * hi + 1];
            float4 n0 = Np[8 * s + 2 * hi], n1 = Np[8 * s + 2 * hi + 1];
            float4 q0 = make_float4(o0.x + n0.x, o0.y + n0.y, o0.z + n0.z, o0.w + n0.w);
            float4 q1 = make_float4(o1.x + n1.x, o1.y + n1.y, o1.z + n1.z, o1.w + n1.w);
            A[s] = pack8(q0, q1);
        }
        f32x4 acc[4];
        #pragma unroll
        for (int u = 0; u < 4; u++) acc[u] = (f32x4){0.f, 0.f, 0.f, 0.f};
        #pragma unroll
        for (int s = 0; s < 2; s++) {
            #pragma unroll
            for (int u = 0; u < 4; u++)
                acc[u] = __builtin_amdgcn_mfma_f32_16x16x32_bf16(A[s], B[s][u], acc[u], 0, 0, 0);
        }
        #pragma unroll
        for (int u = 0; u < 4; u++) {
            #pragma unroll
            for (int reg = 0; reg < 4; reg++)
                qatt[(size_t)(r0 + 4 * hi + reg) * E + 16 * u + lo] =
                    __float2bfloat16(acc[u][reg]);
        }
    }
}

// ---- attention: R4-frozen body. ONLY changes this round (one mechanism:
//      occupancy via VGPR<=64): (1) launch_bounds(256,8) pins allocator;
//      (2) nls[12] array removed -> inline nl=(t*16+lo)/24 (t compile-time). ----
__global__ __launch_bounds__(256, 8) void k_att(const int* __restrict__ nodes,
                                                const int* __restrict__ nidx,
                                                const __hip_bfloat16* __restrict__ comb,
                                                const __hip_bfloat16* __restrict__ qatt,
                                                const bf16x8* __restrict__ B2img,
                                                const float* __restrict__ bw,
                                                const int* __restrict__ winner,
                                                float* __restrict__ outE) {
    __shared__ float s_scores[4][192];
    __shared__ int2  s_iw[4][192];       // .x = neighbor idx, .y = softmax weight bits
    const int wave = threadIdx.x >> 6, lane = threadIdx.x & 63;
    const int lo = lane & 15, hi = lane >> 4;
    const int n0 = (blockIdx.x * 4 + wave) * 8;   // grid = N_NODES/32 exactly

    // B fragments + bias/w3 from precomputed images (10 vector loads total)
    bf16x8 Bf[8];
    #pragma unroll
    for (int f = 0; f < 8; f++) Bf[f] = B2img[f * 64 + lane];
    f32x4 bb = *reinterpret_cast<const f32x4*>(bw + lane * 8);
    f32x4 wv = *reinterpret_cast<const f32x4*>(bw + lane * 8 + 4);

    // prefetch neighbor ids; stage into LDS (row r = nd*24+k == t*16+lo)
    int idxs[12];
    #pragma unroll
    for (int t = 0; t < 12; t++) {
        int r = t * 16 + lo;
        int nl = r / 24;
        idxs[t] = nidx[(size_t)(n0 + nl) * KNEI + (r - nl * 24)];
        s_iw[wave][r].x = idxs[t];
    }

    #pragma unroll
    for (int t = 0; t < 12; t++) {
        const int nl = (t * 16 + lo) / 24;          // t literal -> folds to cmp+add
        const bf16x8* iarow = reinterpret_cast<const bf16x8*>(comb + (size_t)idxs[t] * 128);
        const bf16x8* qrow  = reinterpret_cast<const bf16x8*>(qatt + (size_t)(n0 + nl) * E);
        f32x4 acc[4];
        #pragma unroll
        for (int u = 0; u < 4; u++)
            acc[u] = (f32x4){bb[u], bb[u], bb[u], bb[u]};   // ab2 folded into C-init
        #pragma unroll
        for (int s = 0; s < 2; s++) {
            bf16x8 ia = iarow[4 * s + hi];
            bf16x8 qa = qrow[4 * s + hi];
            bf16x8 a;
            #pragma unroll
            for (int e = 0; e < 8; e++) {
                float v = bf2f(ia[e]) + bf2f(qa[e]);
                a[e] = f2bf(fmaxf(v, 0.f));
            }
            #pragma unroll
            for (int u = 0; u < 4; u++)
                acc[u] = __builtin_amdgcn_mfma_f32_16x16x32_bf16(a, Bf[s * 4 + u], acc[u], 0, 0, 0);
        }
        // score partial: relu(h2+b2) . aW3 over this lane's 16-col slice
        f32x4 sum;
        #pragma unroll
        for (int reg = 0; reg < 4; reg++) {
            float v = 0.f;
            #pragma unroll
            for (int u = 0; u < 4; u++)
                v = fmaf(fmaxf(acc[u][reg], 0.f), wv[u], v);
            sum[reg] = v;
        }
        #pragma unroll
        for (int m = 1; m < 16; m <<= 1) {
            #pragma unroll
            for (int reg = 0; reg < 4; reg++)
                sum[reg] += __shfl_xor(sum[reg], m);
        }
        if (lo == 0)
            *reinterpret_cast<f32x4*>(&s_scores[wave][t * 16 + hi * 4]) = sum;
    }
    // no barrier needed: all LDS traffic is wave-local

    // softmax + weighted aggregation: 2 nodes in parallel (one per 32-lane half)
    const int half = lane >> 5, j = lane & 31;
    for (int p = 0; p < 4; p++) {
        int nd = 2 * p + half;
        int n = n0 + nd;
        float sc = (j < KNEI) ? s_scores[wave][nd * KNEI + j] : -1e30f;
        float mx = sc;
        #pragma unroll
        for (int m = 1; m < 32; m <<= 1) mx = fmaxf(mx, __shfl_xor(mx, m));
        float e = (j < KNEI) ? __expf(sc - mx) : 0.f;
        float ss = e;
        #pragma unroll
        for (int m = 1; m < 32; m <<= 1) ss += __shfl_xor(ss, m);
        float w = e / ss;
        if (j < KNEI) s_iw[wave][nd * KNEI + j].y = __float_as_int(w);

        float emb0 = 0.f, emb1 = 0.f;
        const char* ipb = reinterpret_cast<const char*>(comb);
        #pragma unroll
        for (int k = 0; k < KNEI; k++) {
            int2 iw = s_iw[wave][nd * KNEI + k];      // ds_read_b64 broadcast per half
            float wk = __int_as_float(iw.y);
            unsigned u = *reinterpret_cast<const unsigned*>(
                ipb + (size_t)iw.x * 256 + 128 + j * 4);   // i_proj half: dims 2j, 2j+1
            emb0 = fmaf(wk, __uint_as_float(u << 16), emb0);
            emb1 = fmaf(wk, __uint_as_float(u & 0xFFFF0000u), emb1);
        }
        int un = nodes[n];
        if (winner[un] == n) {
            float2 st = make_float2(emb0, emb1);
            *reinterpret_cast<float2*>(outE + (size_t)un * E + 2 * j) = st;
        }
    }
}

extern "C" void kernel_launch(void* const* d_in, const int* in_sizes, int n_in,
                              void* d_out, int out_size, void* d_ws, size_t ws_size,
                              hipStream_t stream) {
    const int*   nodes = (const int*)d_in[0];
    const float* nfeat = (const float*)d_in[1];
    const int*   nidx  = (const int*)d_in[2];
    const float* uwt   = (const float*)d_in[3];
    const float* iwt   = (const float*)d_in[4];
    const float* uW    = (const float*)d_in[5];
    const float* ub    = (const float*)d_in[6];
    const float* iW    = (const float*)d_in[7];
    const float* ib    = (const float*)d_in[8];
    const float* aW1   = (const float*)d_in[9];
    const float* ab1   = (const float*)d_in[10];
    const float* aW2   = (const float*)d_in[11];
    const float* ab2   = (const float*)d_in[12];
    const float* aW3   = (const float*)d_in[13];
    // d_in[14] = ab3: softmax-shift-invariant, unused

    float* out_nf  = (float*)d_out;
    float* out_emb = out_nf + (size_t)N_NODES * E;

    char* ws = (char*)d_ws;
    __hip_bfloat16* comb  = (__hip_bfloat16*)(ws);
    __hip_bfloat16* qatt  = (__hip_bfloat16*)(ws + 51200000);
    int*            winner = (int*)(ws + 64000000);
    float*          Wp     = (float*)(ws + 64800000);
    float*          bp     = (float*)(ws + 64832768);
    bf16x8*         B2img  = (bf16x8*)(ws + 64833024);
    float*          bwimg  = (float*)(ws + 64841216);

    hipMemsetAsync(winner, 0xFF, (size_t)N_USERS * sizeof(int), stream);
    hipMemsetAsync(out_emb, 0, (size_t)N_USERS * E * sizeof(float), stream);

    k_fuse<<<34, 256, 0, stream>>>(iW, aW1, ib, ab1, aW2, ab2, aW3,
                                   Wp, bp, B2img, bwimg);
    k_item<<<1024, 256, 0, stream>>>(iwt, iW, ib, Wp, bp, comb);
    k_node1<<<512, 256, 0, stream>>>(nodes, uwt, uW, ub, out_nf, winner);
    k_node2<<<512, 256, 0, stream>>>(out_nf, nfeat, aW1, qatt);
    k_att<<<N_NODES / 32, 256, 0, stream>>>(nodes, nidx, comb, qatt,
                                            B2img, bwimg, winner, out_emb);
}

// Round 11
// 219.432 us; speedup vs baseline: 2.2321x; 2.2321x over previous
//
#include <hip/hip_runtime.h>
#include <hip/hip_bf16.h>

#define N_NODES 100000
#define N_USERS 200000
#define N_ITEMS 200000
#define KNEI 24
#define E 64
#define F 128

typedef __attribute__((ext_vector_type(8))) short bf16x8;
typedef __attribute__((ext_vector_type(4))) float f32x4;

// ---- workspace layout (bytes) ----
// comb   bf16 [N_ITEMS][128]: off 0          size 51,200,000  (row = [i_att(64) | i_proj(64)])
// q_att  bf16 [N_NODES][64] : off 51,200,000 size 12,800,000
//        (after k_score, row n's first 96 B are REUSED as wgt[n][24] f32)
// winner int  [N_USERS]     : off 64,000,000 size    800,000
// W'     f32  [128][64]     : off 64,800,000 size     32,768
// b'     f32  [64]          : off 64,832,768 size        256
// B2img  bf16 [8][64][8]    : off 64,833,024 size      8,192   (aW2 B-frag image)
// bw     f32  [64][8]       : off 64,841,216 size      2,048   (ab2|aW3 splat image)

__device__ inline float bf2f(short s) {
    unsigned u = ((unsigned)(unsigned short)s) << 16;
    return __uint_as_float(u);
}
__device__ inline short f2bf(float f) {
    __hip_bfloat16 h = __float2bfloat16(f);
    return *reinterpret_cast<short*>(&h);
}
__device__ inline bf16x8 pack8(float4 a, float4 b) {
    bf16x8 r;
    r[0] = f2bf(a.x); r[1] = f2bf(a.y); r[2] = f2bf(a.z); r[3] = f2bf(a.w);
    r[4] = f2bf(b.x); r[5] = f2bf(b.y); r[6] = f2bf(b.z); r[7] = f2bf(b.w);
    return r;
}

// ---- fuse: W' = iW@aW1a ; b' = ib@aW1a + ab1 ; aW2 frag image ; ab2/aW3 splat image ----
__global__ __launch_bounds__(256) void k_fuse(const float* __restrict__ iW,
                                              const float* __restrict__ aW1,
                                              const float* __restrict__ ib,
                                              const float* __restrict__ ab1,
                                              const float* __restrict__ aW2,
                                              const float* __restrict__ ab2,
                                              const float* __restrict__ aW3,
                                              float* __restrict__ Wp,
                                              float* __restrict__ bp,
                                              bf16x8* __restrict__ B2img,
                                              float* __restrict__ bw) {
    int g = blockIdx.x * 256 + threadIdx.x;
    if (g < 8192) {
        int f = g >> 6, c = g & 63;
        float s = 0.f;
        for (int j = 0; j < 64; j++) s = fmaf(iW[f * 64 + j], aW1[j * 64 + c], s);
        Wp[g] = s;
        if (g < 64) {
            float b = ab1[g];
            for (int j = 0; j < 64; j++) b = fmaf(ib[j], aW1[j * 64 + g], b);
            bp[g] = b;
        }
    } else if (g < 8192 + 512) {
        int h = g - 8192;
        int f = h >> 6, l = h & 63;
        int s = f >> 2, u = f & 3;
        int lo = l & 15, hi = l >> 4;
        bf16x8 b;
        #pragma unroll
        for (int e = 0; e < 8; e++)
            b[e] = f2bf(aW2[(size_t)(32 * s + 8 * hi + e) * 64 + 16 * u + lo]);
        B2img[h] = b;
        if (f == 0) {
            #pragma unroll
            for (int uu = 0; uu < 4; uu++) {
                bw[l * 8 + uu]     = ab2[16 * uu + lo];
                bw[l * 8 + 4 + uu] = aW3[16 * uu + lo];
            }
        }
    }
}

// MFMA lane mappings (correctness-proven rounds 2-10):
//   A frag 16x16x32: lane l -> row = l&15, k = 8*(l>>4)+e
//   B frag:          lane l -> col = l&15, k = 8*(l>>4)+e
//   C/D:             lane l -> col = l&15, row = 4*(l>>4)+reg

// ---- per-item: comb row = [i_att | i_proj] (one A pass, interleaved store) ----
__global__ __launch_bounds__(256, 2) void k_item(const float* __restrict__ iwt,
                                                 const float* __restrict__ iW,
                                                 const float* __restrict__ ib,
                                                 const float* __restrict__ Wp,
                                                 const float* __restrict__ bp,
                                                 __hip_bfloat16* __restrict__ comb) {
    const int wave = threadIdx.x >> 6, lane = threadIdx.x & 63;
    const int lo = lane & 15, hi = lane >> 4;

    bf16x8 B1[4][4], B2[4][4];
    #pragma unroll
    for (int s = 0; s < 4; s++) {
        #pragma unroll
        for (int u = 0; u < 4; u++) {
            bf16x8 b1, b2;
            #pragma unroll
            for (int e = 0; e < 8; e++) {
                int k = 32 * s + 8 * hi + e;
                b1[e] = f2bf(iW[k * 64 + 16 * u + lo]);
                b2[e] = f2bf(Wp[k * 64 + 16 * u + lo]);
            }
            B1[s][u] = b1; B2[s][u] = b2;
        }
    }
    float bi[4], ba[4];
    #pragma unroll
    for (int u = 0; u < 4; u++) { bi[u] = ib[16 * u + lo]; ba[u] = bp[16 * u + lo]; }

    const int wid = blockIdx.x * 4 + wave;
    for (int t = wid; t < N_ITEMS / 16; t += 1024 * 4) {
        int r0 = t * 16;
        const float4* Ap = reinterpret_cast<const float4*>(iwt + (size_t)(r0 + lo) * F);
        bf16x8 A[4];
        #pragma unroll
        for (int s = 0; s < 4; s++)
            A[s] = pack8(Ap[8 * s + 2 * hi], Ap[8 * s + 2 * hi + 1]);
        f32x4 acc1[4], acc2[4];
        #pragma unroll
        for (int u = 0; u < 4; u++) {
            acc1[u] = (f32x4){bi[u], bi[u], bi[u], bi[u]};
            acc2[u] = (f32x4){ba[u], ba[u], ba[u], ba[u]};
        }
        #pragma unroll
        for (int s = 0; s < 4; s++) {
            #pragma unroll
            for (int u = 0; u < 4; u++) {
                acc1[u] = __builtin_amdgcn_mfma_f32_16x16x32_bf16(A[s], B1[s][u], acc1[u], 0, 0, 0);
                acc2[u] = __builtin_amdgcn_mfma_f32_16x16x32_bf16(A[s], B2[s][u], acc2[u], 0, 0, 0);
            }
        }
        #pragma unroll
        for (int u = 0; u < 4; u++) {
            #pragma unroll
            for (int reg = 0; reg < 4; reg++) {
                size_t off = (size_t)(r0 + 4 * hi + reg) * 128 + 16 * u + lo;
                comb[off]      = __float2bfloat16(acc2[u][reg]);   // i_att half
                comb[off + 64] = __float2bfloat16(acc1[u][reg]);   // i_proj half
            }
        }
    }
}

// ---- per-node pass 1: nodes_fea = u_weight[nodes]@uW + ub (f32 out) + winner ----
__global__ __launch_bounds__(256, 2) void k_node1(const int* __restrict__ nodes,
                                                  const float* __restrict__ uwt,
                                                  const float* __restrict__ uW,
                                                  const float* __restrict__ ub,
                                                  float* __restrict__ out_nf,
                                                  int* __restrict__ winner) {
    const int wave = threadIdx.x >> 6, lane = threadIdx.x & 63;
    const int lo = lane & 15, hi = lane >> 4;

    bf16x8 B[4][4];
    #pragma unroll
    for (int s = 0; s < 4; s++) {
        #pragma unroll
        for (int u = 0; u < 4; u++) {
            bf16x8 b;
            #pragma unroll
            for (int e = 0; e < 8; e++) {
                int k = 32 * s + 8 * hi + e;
                b[e] = f2bf(uW[k * 64 + 16 * u + lo]);
            }
            B[s][u] = b;
        }
    }
    float bu[4];
    #pragma unroll
    for (int u = 0; u < 4; u++) bu[u] = ub[16 * u + lo];

    const int wid = blockIdx.x * 4 + wave;
    for (int t = wid; t < N_NODES / 16; t += 512 * 4) {
        int r0 = t * 16;
        int n = r0 + lo;
        int un = nodes[n];
        if (hi == 0) atomicMax(&winner[un], n);
        const float4* Ap = reinterpret_cast<const float4*>(uwt + (size_t)un * F);
        bf16x8 A[4];
        #pragma unroll
        for (int s = 0; s < 4; s++)
            A[s] = pack8(Ap[8 * s + 2 * hi], Ap[8 * s + 2 * hi + 1]);
        f32x4 acc[4];
        #pragma unroll
        for (int u = 0; u < 4; u++) acc[u] = (f32x4){bu[u], bu[u], bu[u], bu[u]};
        #pragma unroll
        for (int s = 0; s < 4; s++) {
            #pragma unroll
            for (int u = 0; u < 4; u++)
                acc[u] = __builtin_amdgcn_mfma_f32_16x16x32_bf16(A[s], B[s][u], acc[u], 0, 0, 0);
        }
        #pragma unroll
        for (int u = 0; u < 4; u++) {
            #pragma unroll
            for (int reg = 0; reg < 4; reg++)
                out_nf[(size_t)(r0 + 4 * hi + reg) * E + 16 * u + lo] = acc[u][reg];
        }
    }
}

// ---- per-node pass 2: q_att = (nodes_fea + n_feature) @ aW1[64:] (bf16 ws) ----
__global__ __launch_bounds__(256, 2) void k_node2(const float* __restrict__ out_nf,
                                                  const float* __restrict__ nfeat,
                                                  const float* __restrict__ aW1,
                                                  __hip_bfloat16* __restrict__ qatt) {
    const int wave = threadIdx.x >> 6, lane = threadIdx.x & 63;
    const int lo = lane & 15, hi = lane >> 4;

    bf16x8 B[2][4];
    #pragma unroll
    for (int s = 0; s < 2; s++) {
        #pragma unroll
        for (int u = 0; u < 4; u++) {
            bf16x8 b;
            #pragma unroll
            for (int e = 0; e < 8; e++) {
                int k = 32 * s + 8 * hi + e;
                b[e] = f2bf(aW1[(size_t)(E + k) * 64 + 16 * u + lo]);
            }
            B[s][u] = b;
        }
    }

    const int wid = blockIdx.x * 4 + wave;
    for (int t = wid; t < N_NODES / 16; t += 512 * 4) {
        int r0 = t * 16;
        const float4* Op = reinterpret_cast<const float4*>(out_nf + (size_t)(r0 + lo) * E);
        const float4* Np = reinterpret_cast<const float4*>(nfeat + (size_t)(r0 + lo) * E);
        bf16x8 A[2];
        #pragma unroll
        for (int s = 0; s < 2; s++) {
            float4 o0 = Op[8 * s + 2 * hi], o1 = Op[8 * s + 2 * hi + 1];
            float4 n0 = Np[8 * s + 2 * hi], n1 = Np[8 * s + 2 * hi + 1];
            float4 q0 = make_float4(o0.x + n0.x, o0.y + n0.y, o0.z + n0.z, o0.w + n0.w);
            float4 q1 = make_float4(o1.x + n1.x, o1.y + n1.y, o1.z + n1.z, o1.w + n1.w);
            A[s] = pack8(q0, q1);
        }
        f32x4 acc[4];
        #pragma unroll
        for (int u = 0; u < 4; u++) acc[u] = (f32x4){0.f, 0.f, 0.f, 0.f};
        #pragma unroll
        for (int s = 0; s < 2; s++) {
            #pragma unroll
            for (int u = 0; u < 4; u++)
                acc[u] = __builtin_amdgcn_mfma_f32_16x16x32_bf16(A[s], B[s][u], acc[u], 0, 0, 0);
        }
        #pragma unroll
        for (int u = 0; u < 4; u++) {
            #pragma unroll
            for (int reg = 0; reg < 4; reg++)
                qatt[(size_t)(r0 + 4 * hi + reg) * E + 16 * u + lo] =
                    __float2bfloat16(acc[u][reg]);
        }
    }
}

// ---- score: R4-frozen score loop + softmax. Agg phase removed (see k_agg).
//      Softmax weights overwrite the (now-dead) qatt row of the same node:
//      wave reads qatt rows n0..n0+7 only, then writes wgt into those rows. ----
__global__ __launch_bounds__(256) void k_score(const int* __restrict__ nidx,
                                               const __hip_bfloat16* __restrict__ comb,
                                               __hip_bfloat16* qatt,
                                               const bf16x8* __restrict__ B2img,
                                               const float* __restrict__ bw) {
    __shared__ float s_scores[4][192];
    const int wave = threadIdx.x >> 6, lane = threadIdx.x & 63;
    const int lo = lane & 15, hi = lane >> 4;
    const int n0 = (blockIdx.x * 4 + wave) * 8;   // grid = N_NODES/32 exactly

    // B fragments + bias/w3 from precomputed images (10 vector loads total)
    bf16x8 Bf[8];
    #pragma unroll
    for (int f = 0; f < 8; f++) Bf[f] = B2img[f * 64 + lane];
    f32x4 bb = *reinterpret_cast<const f32x4*>(bw + lane * 8);
    f32x4 wv = *reinterpret_cast<const f32x4*>(bw + lane * 8 + 4);

    // prefetch neighbor ids for all 12 tiles (registers)
    int idxs[12];
    #pragma unroll
    for (int t = 0; t < 12; t++) {
        int r = t * 16 + lo;
        int nl = r / 24;
        idxs[t] = nidx[(size_t)(n0 + nl) * KNEI + (r - nl * 24)];
    }

    #pragma unroll
    for (int t = 0; t < 12; t++) {
        const int nl = (t * 16 + lo) / 24;          // t literal -> folds
        const bf16x8* iarow = reinterpret_cast<const bf16x8*>(comb + (size_t)idxs[t] * 128);
        const bf16x8* qrow  = reinterpret_cast<const bf16x8*>(qatt + (size_t)(n0 + nl) * E);
        f32x4 acc[4];
        #pragma unroll
        for (int u = 0; u < 4; u++)
            acc[u] = (f32x4){bb[u], bb[u], bb[u], bb[u]};   // ab2 folded into C-init
        #pragma unroll
        for (int s = 0; s < 2; s++) {
            bf16x8 ia = iarow[4 * s + hi];
            bf16x8 qa = qrow[4 * s + hi];
            bf16x8 a;
            #pragma unroll
            for (int e = 0; e < 8; e++) {
                float v = bf2f(ia[e]) + bf2f(qa[e]);
                a[e] = f2bf(fmaxf(v, 0.f));
            }
            #pragma unroll
            for (int u = 0; u < 4; u++)
                acc[u] = __builtin_amdgcn_mfma_f32_16x16x32_bf16(a, Bf[s * 4 + u], acc[u], 0, 0, 0);
        }
        // score partial: relu(h2+b2) . aW3 over this lane's 16-col slice
        f32x4 sum;
        #pragma unroll
        for (int reg = 0; reg < 4; reg++) {
            float v = 0.f;
            #pragma unroll
            for (int u = 0; u < 4; u++)
                v = fmaf(fmaxf(acc[u][reg], 0.f), wv[u], v);
            sum[reg] = v;
        }
        #pragma unroll
        for (int m = 1; m < 16; m <<= 1) {
            #pragma unroll
            for (int reg = 0; reg < 4; reg++)
                sum[reg] += __shfl_xor(sum[reg], m);
        }
        if (lo == 0)
            *reinterpret_cast<f32x4*>(&s_scores[wave][t * 16 + hi * 4]) = sum;
    }
    // no barrier needed: all LDS traffic is wave-local

    // softmax per 32-lane half (2 nodes in parallel); weights overwrite qatt row n
    const int half = lane >> 5, j = lane & 31;
    #pragma unroll
    for (int p = 0; p < 4; p++) {
        int nd = 2 * p + half;
        int n = n0 + nd;
        float sc = (j < KNEI) ? s_scores[wave][nd * KNEI + j] : -1e30f;
        float mx = sc;
        #pragma unroll
        for (int m = 1; m < 32; m <<= 1) mx = fmaxf(mx, __shfl_xor(mx, m));
        float e = (j < KNEI) ? __expf(sc - mx) : 0.f;
        float ss = e;
        #pragma unroll
        for (int m = 1; m < 32; m <<= 1) ss += __shfl_xor(ss, m);
        if (j < KNEI) {
            float* wrow = reinterpret_cast<float*>(
                reinterpret_cast<char*>(qatt) + (size_t)n * 128);
            wrow[j] = e / ss;
        }
    }
}

// ---- agg: one user per 16-lane quarter; winner-less users write zeros
//      (replaces out_emb memset). ~20 VGPR -> near-max occupancy. ----
__global__ __launch_bounds__(256) void k_agg(const int* __restrict__ winner,
                                             const int* __restrict__ nidx,
                                             const __hip_bfloat16* __restrict__ qatt, // wgt overlay
                                             const __hip_bfloat16* __restrict__ comb,
                                             float* __restrict__ outE) {
    const int qd = threadIdx.x >> 4, jj = threadIdx.x & 15;
    const int u = blockIdx.x * 16 + qd;          // grid = N_USERS/16 exactly
    int wn = winner[u];
    float4 emb = make_float4(0.f, 0.f, 0.f, 0.f);
    if (wn >= 0) {
        const float* wrow = reinterpret_cast<const float*>(
            reinterpret_cast<const char*>(qatt) + (size_t)wn * 128);
        const int* irow = nidx + (size_t)wn * KNEI;
        const char* cb = reinterpret_cast<const char*>(comb);
        #pragma unroll
        for (int k = 0; k < KNEI; k++) {
            int idx = irow[k];                    // uniform within quarter
            float w = wrow[k];
            uint2 uv = *reinterpret_cast<const uint2*>(
                cb + (size_t)idx * 256 + 128 + jj * 8);   // iproj dims 4jj..4jj+3
            emb.x = fmaf(w, __uint_as_float(uv.x << 16), emb.x);
            emb.y = fmaf(w, __uint_as_float(uv.x & 0xFFFF0000u), emb.y);
            emb.z = fmaf(w, __uint_as_float(uv.y << 16), emb.z);
            emb.w = fmaf(w, __uint_as_float(uv.y & 0xFFFF0000u), emb.w);
        }
    }
    *reinterpret_cast<float4*>(outE + (size_t)u * E + 4 * jj) = emb;
}

extern "C" void kernel_launch(void* const* d_in, const int* in_sizes, int n_in,
                              void* d_out, int out_size, void* d_ws, size_t ws_size,
                              hipStream_t stream) {
    const int*   nodes = (const int*)d_in[0];
    const float* nfeat = (const float*)d_in[1];
    const int*   nidx  = (const int*)d_in[2];
    const float* uwt   = (const float*)d_in[3];
    const float* iwt   = (const float*)d_in[4];
    const float* uW    = (const float*)d_in[5];
    const float* ub    = (const float*)d_in[6];
    const float* iW    = (const float*)d_in[7];
    const float* ib    = (const float*)d_in[8];
    const float* aW1   = (const float*)d_in[9];
    const float* ab1   = (const float*)d_in[10];
    const float* aW2   = (const float*)d_in[11];
    const float* ab2   = (const float*)d_in[12];
    const float* aW3   = (const float*)d_in[13];
    // d_in[14] = ab3: softmax-shift-invariant, unused

    float* out_nf  = (float*)d_out;
    float* out_emb = out_nf + (size_t)N_NODES * E;

    char* ws = (char*)d_ws;
    __hip_bfloat16* comb  = (__hip_bfloat16*)(ws);
    __hip_bfloat16* qatt  = (__hip_bfloat16*)(ws + 51200000);
    int*            winner = (int*)(ws + 64000000);
    float*          Wp     = (float*)(ws + 64800000);
    float*          bp     = (float*)(ws + 64832768);
    bf16x8*         B2img  = (bf16x8*)(ws + 64833024);
    float*          bwimg  = (float*)(ws + 64841216);

    hipMemsetAsync(winner, 0xFF, (size_t)N_USERS * sizeof(int), stream);

    k_fuse<<<34, 256, 0, stream>>>(iW, aW1, ib, ab1, aW2, ab2, aW3,
                                   Wp, bp, B2img, bwimg);
    k_item<<<1024, 256, 0, stream>>>(iwt, iW, ib, Wp, bp, comb);
    k_node1<<<512, 256, 0, stream>>>(nodes, uwt, uW, ub, out_nf, winner);
    k_node2<<<512, 256, 0, stream>>>(out_nf, nfeat, aW1, qatt);
    k_score<<<N_NODES / 32, 256, 0, stream>>>(nidx, comb, qatt, B2img, bwimg);
    k_agg<<<N_USERS / 16, 256, 0, stream>>>(winner, nidx, qatt, comb, out_emb);
}

// Round 12
// 209.665 us; speedup vs baseline: 2.3361x; 1.0466x over previous
//
#include <hip/hip_runtime.h>
#include <hip/hip_bf16.h>

#define N_NODES 100000
#define N_USERS 200000
#define N_ITEMS 200000
#define KNEI 24
#define E 64
#define F 128

typedef __attribute__((ext_vector_type(8))) short bf16x8;
typedef __attribute__((ext_vector_type(4))) float f32x4;

// ---- workspace layout (bytes) ----
// comb   bf16 [N_ITEMS][128]: off 0          size 51,200,000  (row = [i_att(64) | i_proj(64)])
// q_att  bf16 [N_NODES][64] : off 51,200,000 size 12,800,000
// winner int  [N_USERS]     : off 64,000,000 size    800,000
// W'     f32  [128][64]     : off 64,800,000 size     32,768
// b'     f32  [64]          : off 64,832,768 size        256
// B2img  bf16 [8][64][8]    : off 64,833,024 size      8,192   (aW2 B-frag image)
// bw     f32  [64][8]       : off 64,841,216 size      2,048   (ab2|aW3 splat image)

__device__ inline float bf2f(short s) {
    unsigned u = ((unsigned)(unsigned short)s) << 16;
    return __uint_as_float(u);
}
__device__ inline short f2bf(float f) {
    __hip_bfloat16 h = __float2bfloat16(f);
    return *reinterpret_cast<short*>(&h);
}
__device__ inline bf16x8 pack8(float4 a, float4 b) {
    bf16x8 r;
    r[0] = f2bf(a.x); r[1] = f2bf(a.y); r[2] = f2bf(a.z); r[3] = f2bf(a.w);
    r[4] = f2bf(b.x); r[5] = f2bf(b.y); r[6] = f2bf(b.z); r[7] = f2bf(b.w);
    return r;
}

// ---- fuse: W' = iW@aW1a ; b' = ib@aW1a + ab1 ; aW2 frag image ; ab2/aW3 splat image ----
__global__ __launch_bounds__(256) void k_fuse(const float* __restrict__ iW,
                                              const float* __restrict__ aW1,
                                              const float* __restrict__ ib,
                                              const float* __restrict__ ab1,
                                              const float* __restrict__ aW2,
                                              const float* __restrict__ ab2,
                                              const float* __restrict__ aW3,
                                              float* __restrict__ Wp,
                                              float* __restrict__ bp,
                                              bf16x8* __restrict__ B2img,
                                              float* __restrict__ bw) {
    int g = blockIdx.x * 256 + threadIdx.x;
    if (g < 8192) {
        int f = g >> 6, c = g & 63;
        float s = 0.f;
        for (int j = 0; j < 64; j++) s = fmaf(iW[f * 64 + j], aW1[j * 64 + c], s);
        Wp[g] = s;
        if (g < 64) {
            float b = ab1[g];
            for (int j = 0; j < 64; j++) b = fmaf(ib[j], aW1[j * 64 + g], b);
            bp[g] = b;
        }
    } else if (g < 8192 + 512) {
        int h = g - 8192;
        int f = h >> 6, l = h & 63;
        int s = f >> 2, u = f & 3;
        int lo = l & 15, hi = l >> 4;
        bf16x8 b;
        #pragma unroll
        for (int e = 0; e < 8; e++)
            b[e] = f2bf(aW2[(size_t)(32 * s + 8 * hi + e) * 64 + 16 * u + lo]);
        B2img[h] = b;
        if (f == 0) {
            #pragma unroll
            for (int uu = 0; uu < 4; uu++) {
                bw[l * 8 + uu]     = ab2[16 * uu + lo];
                bw[l * 8 + 4 + uu] = aW3[16 * uu + lo];
            }
        }
    }
}

// MFMA lane mappings (correctness-proven rounds 2-11):
//   A frag 16x16x32: lane l -> row = l&15, k = 8*(l>>4)+e
//   B frag:          lane l -> col = l&15, k = 8*(l>>4)+e
//   C/D:             lane l -> col = l&15, row = 4*(l>>4)+reg

// ---- per-item: comb row = [i_att | i_proj] (one A pass, interleaved store) ----
__global__ __launch_bounds__(256, 2) void k_item(const float* __restrict__ iwt,
                                                 const float* __restrict__ iW,
                                                 const float* __restrict__ ib,
                                                 const float* __restrict__ Wp,
                                                 const float* __restrict__ bp,
                                                 __hip_bfloat16* __restrict__ comb) {
    const int wave = threadIdx.x >> 6, lane = threadIdx.x & 63;
    const int lo = lane & 15, hi = lane >> 4;

    bf16x8 B1[4][4], B2[4][4];
    #pragma unroll
    for (int s = 0; s < 4; s++) {
        #pragma unroll
        for (int u = 0; u < 4; u++) {
            bf16x8 b1, b2;
            #pragma unroll
            for (int e = 0; e < 8; e++) {
                int k = 32 * s + 8 * hi + e;
                b1[e] = f2bf(iW[k * 64 + 16 * u + lo]);
                b2[e] = f2bf(Wp[k * 64 + 16 * u + lo]);
            }
            B1[s][u] = b1; B2[s][u] = b2;
        }
    }
    float bi[4], ba[4];
    #pragma unroll
    for (int u = 0; u < 4; u++) { bi[u] = ib[16 * u + lo]; ba[u] = bp[16 * u + lo]; }

    const int wid = blockIdx.x * 4 + wave;
    for (int t = wid; t < N_ITEMS / 16; t += 1024 * 4) {
        int r0 = t * 16;
        const float4* Ap = reinterpret_cast<const float4*>(iwt + (size_t)(r0 + lo) * F);
        bf16x8 A[4];
        #pragma unroll
        for (int s = 0; s < 4; s++)
            A[s] = pack8(Ap[8 * s + 2 * hi], Ap[8 * s + 2 * hi + 1]);
        f32x4 acc1[4], acc2[4];
        #pragma unroll
        for (int u = 0; u < 4; u++) {
            acc1[u] = (f32x4){bi[u], bi[u], bi[u], bi[u]};
            acc2[u] = (f32x4){ba[u], ba[u], ba[u], ba[u]};
        }
        #pragma unroll
        for (int s = 0; s < 4; s++) {
            #pragma unroll
            for (int u = 0; u < 4; u++) {
                acc1[u] = __builtin_amdgcn_mfma_f32_16x16x32_bf16(A[s], B1[s][u], acc1[u], 0, 0, 0);
                acc2[u] = __builtin_amdgcn_mfma_f32_16x16x32_bf16(A[s], B2[s][u], acc2[u], 0, 0, 0);
            }
        }
        #pragma unroll
        for (int u = 0; u < 4; u++) {
            #pragma unroll
            for (int reg = 0; reg < 4; reg++) {
                size_t off = (size_t)(r0 + 4 * hi + reg) * 128 + 16 * u + lo;
                comb[off]      = __float2bfloat16(acc2[u][reg]);   // i_att half
                comb[off + 64] = __float2bfloat16(acc1[u][reg]);   // i_proj half
            }
        }
    }
}

// ---- per-node pass 1: nodes_fea = u_weight[nodes]@uW + ub (f32 out) + winner ----
__global__ __launch_bounds__(256, 2) void k_node1(const int* __restrict__ nodes,
                                                  const float* __restrict__ uwt,
                                                  const float* __restrict__ uW,
                                                  const float* __restrict__ ub,
                                                  float* __restrict__ out_nf,
                                                  int* __restrict__ winner) {
    const int wave = threadIdx.x >> 6, lane = threadIdx.x & 63;
    const int lo = lane & 15, hi = lane >> 4;

    bf16x8 B[4][4];
    #pragma unroll
    for (int s = 0; s < 4; s++) {
        #pragma unroll
        for (int u = 0; u < 4; u++) {
            bf16x8 b;
            #pragma unroll
            for (int e = 0; e < 8; e++) {
                int k = 32 * s + 8 * hi + e;
                b[e] = f2bf(uW[k * 64 + 16 * u + lo]);
            }
            B[s][u] = b;
        }
    }
    float bu[4];
    #pragma unroll
    for (int u = 0; u < 4; u++) bu[u] = ub[16 * u + lo];

    const int wid = blockIdx.x * 4 + wave;
    for (int t = wid; t < N_NODES / 16; t += 512 * 4) {
        int r0 = t * 16;
        int n = r0 + lo;
        int un = nodes[n];
        if (hi == 0) atomicMax(&winner[un], n);
        const float4* Ap = reinterpret_cast<const float4*>(uwt + (size_t)un * F);
        bf16x8 A[4];
        #pragma unroll
        for (int s = 0; s < 4; s++)
            A[s] = pack8(Ap[8 * s + 2 * hi], Ap[8 * s + 2 * hi + 1]);
        f32x4 acc[4];
        #pragma unroll
        for (int u = 0; u < 4; u++) acc[u] = (f32x4){bu[u], bu[u], bu[u], bu[u]};
        #pragma unroll
        for (int s = 0; s < 4; s++) {
            #pragma unroll
            for (int u = 0; u < 4; u++)
                acc[u] = __builtin_amdgcn_mfma_f32_16x16x32_bf16(A[s], B[s][u], acc[u], 0, 0, 0);
        }
        #pragma unroll
        for (int u = 0; u < 4; u++) {
            #pragma unroll
            for (int reg = 0; reg < 4; reg++)
                out_nf[(size_t)(r0 + 4 * hi + reg) * E + 16 * u + lo] = acc[u][reg];
        }
    }
}

// ---- per-node pass 2: q_att = (nodes_fea + n_feature) @ aW1[64:] (bf16 ws) ----
__global__ __launch_bounds__(256, 2) void k_node2(const float* __restrict__ out_nf,
                                                  const float* __restrict__ nfeat,
                                                  const float* __restrict__ aW1,
                                                  __hip_bfloat16* __restrict__ qatt) {
    const int wave = threadIdx.x >> 6, lane = threadIdx.x & 63;
    const int lo = lane & 15, hi = lane >> 4;

    bf16x8 B[2][4];
    #pragma unroll
    for (int s = 0; s < 2; s++) {
        #pragma unroll
        for (int u = 0; u < 4; u++) {
            bf16x8 b;
            #pragma unroll
            for (int e = 0; e < 8; e++) {
                int k = 32 * s + 8 * hi + e;
                b[e] = f2bf(aW1[(size_t)(E + k) * 64 + 16 * u + lo]);
            }
            B[s][u] = b;
        }
    }

    const int wid = blockIdx.x * 4 + wave;
    for (int t = wid; t < N_NODES / 16; t += 512 * 4) {
        int r0 = t * 16;
        const float4* Op = reinterpret_cast<const float4*>(out_nf + (size_t)(r0 + lo) * E);
        const float4* Np = reinterpret_cast<const float4*>(nfeat + (size_t)(r0 + lo) * E);
        bf16x8 A[2];
        #pragma unroll
        for (int s = 0; s < 2; s++) {
            float4 o0 = Op[8 * s + 2 * hi], o1 = Op[8 * s + 2 * hi + 1];
            float4 n0 = Np[8 * s + 2 * hi], n1 = Np[8 * s + 2 * hi + 1];
            float4 q0 = make_float4(o0.x + n0.x, o0.y + n0.y, o0.z + n0.z, o0.w + n0.w);
            float4 q1 = make_float4(o1.x + n1.x, o1.y + n1.y, o1.z + n1.z, o1.w + n1.w);
            A[s] = pack8(q0, q1);
        }
        f32x4 acc[4];
        #pragma unroll
        for (int u = 0; u < 4; u++) acc[u] = (f32x4){0.f, 0.f, 0.f, 0.f};
        #pragma unroll
        for (int s = 0; s < 2; s++) {
            #pragma unroll
            for (int u = 0; u < 4; u++)
                acc[u] = __builtin_amdgcn_mfma_f32_16x16x32_bf16(A[s], B[s][u], acc[u], 0, 0, 0);
        }
        #pragma unroll
        for (int u = 0; u < 4; u++) {
            #pragma unroll
            for (int reg = 0; reg < 4; reg++)
                qatt[(size_t)(r0 + 4 * hi + reg) * E + 16 * u + lo] =
                    __float2bfloat16(acc[u][reg]);
        }
    }
}

// ---- attention: R9-proven fused body (score + softmax + agg). ONLY delta this
//      round: the per-node softmax+agg body is gated on winner[nodes[n]]==n
//      (uniform per 32-lane half; skips ~21% of agg gathers + softmax). ----
__global__ __launch_bounds__(256) void k_att(const int* __restrict__ nodes,
                                             const int* __restrict__ nidx,
                                             const __hip_bfloat16* __restrict__ comb,
                                             const __hip_bfloat16* __restrict__ qatt,
                                             const bf16x8* __restrict__ B2img,
                                             const float* __restrict__ bw,
                                             const int* __restrict__ winner,
                                             float* __restrict__ outE) {
    __shared__ float s_scores[4][192];
    __shared__ int2  s_iw[4][192];       // .x = neighbor idx, .y = softmax weight bits
    const int wave = threadIdx.x >> 6, lane = threadIdx.x & 63;
    const int lo = lane & 15, hi = lane >> 4;
    const int n0 = (blockIdx.x * 4 + wave) * 8;   // grid = N_NODES/32 exactly

    // B fragments + bias/w3 from precomputed images (10 vector loads total)
    bf16x8 Bf[8];
    #pragma unroll
    for (int f = 0; f < 8; f++) Bf[f] = B2img[f * 64 + lane];
    f32x4 bb = *reinterpret_cast<const f32x4*>(bw + lane * 8);
    f32x4 wv = *reinterpret_cast<const f32x4*>(bw + lane * 8 + 4);

    // prefetch neighbor ids; stage into LDS (row r = nd*24+k == t*16+lo)
    int idxs[12], nls[12];
    #pragma unroll
    for (int t = 0; t < 12; t++) {
        int r = t * 16 + lo;
        int nl = r / 24;
        nls[t] = nl;
        idxs[t] = nidx[(size_t)(n0 + nl) * KNEI + (r - nl * 24)];
        s_iw[wave][r].x = idxs[t];
    }

    #pragma unroll
    for (int t = 0; t < 12; t++) {
        const bf16x8* iarow = reinterpret_cast<const bf16x8*>(comb + (size_t)idxs[t] * 128);
        const bf16x8* qrow  = reinterpret_cast<const bf16x8*>(qatt + (size_t)(n0 + nls[t]) * E);
        f32x4 acc[4];
        #pragma unroll
        for (int u = 0; u < 4; u++)
            acc[u] = (f32x4){bb[u], bb[u], bb[u], bb[u]};   // ab2 folded into C-init
        #pragma unroll
        for (int s = 0; s < 2; s++) {
            bf16x8 ia = iarow[4 * s + hi];
            bf16x8 qa = qrow[4 * s + hi];
            bf16x8 a;
            #pragma unroll
            for (int e = 0; e < 8; e++) {
                float v = bf2f(ia[e]) + bf2f(qa[e]);
                a[e] = f2bf(fmaxf(v, 0.f));
            }
            #pragma unroll
            for (int u = 0; u < 4; u++)
                acc[u] = __builtin_amdgcn_mfma_f32_16x16x32_bf16(a, Bf[s * 4 + u], acc[u], 0, 0, 0);
        }
        // score partial: relu(h2+b2) . aW3 over this lane's 16-col slice
        f32x4 sum;
        #pragma unroll
        for (int reg = 0; reg < 4; reg++) {
            float v = 0.f;
            #pragma unroll
            for (int u = 0; u < 4; u++)
                v = fmaf(fmaxf(acc[u][reg], 0.f), wv[u], v);
            sum[reg] = v;
        }
        #pragma unroll
        for (int m = 1; m < 16; m <<= 1) {
            #pragma unroll
            for (int reg = 0; reg < 4; reg++)
                sum[reg] += __shfl_xor(sum[reg], m);
        }
        if (lo == 0)
            *reinterpret_cast<f32x4*>(&s_scores[wave][t * 16 + hi * 4]) = sum;
    }
    // no barrier needed: all LDS traffic is wave-local

    // softmax + weighted aggregation: 2 nodes in parallel (one per 32-lane half),
    // gated on winner (uniform branch per half; losers skip everything)
    const int half = lane >> 5, j = lane & 31;
    for (int p = 0; p < 4; p++) {
        int nd = 2 * p + half;
        int n = n0 + nd;
        int un = nodes[n];
        if (winner[un] == n) {
            float sc = (j < KNEI) ? s_scores[wave][nd * KNEI + j] : -1e30f;
            float mx = sc;
            #pragma unroll
            for (int m = 1; m < 32; m <<= 1) mx = fmaxf(mx, __shfl_xor(mx, m));
            float e = (j < KNEI) ? __expf(sc - mx) : 0.f;
            float ss = e;
            #pragma unroll
            for (int m = 1; m < 32; m <<= 1) ss += __shfl_xor(ss, m);
            float w = e / ss;
            if (j < KNEI) s_iw[wave][nd * KNEI + j].y = __float_as_int(w);

            float emb0 = 0.f, emb1 = 0.f;
            const char* ipb = reinterpret_cast<const char*>(comb);
            #pragma unroll
            for (int k = 0; k < KNEI; k++) {
                int2 iw = s_iw[wave][nd * KNEI + k];      // ds_read_b64 broadcast per half
                float wk = __int_as_float(iw.y);
                unsigned u = *reinterpret_cast<const unsigned*>(
                    ipb + (size_t)iw.x * 256 + 128 + j * 4);   // i_proj half: dims 2j, 2j+1
                emb0 = fmaf(wk, __uint_as_float(u << 16), emb0);
                emb1 = fmaf(wk, __uint_as_float(u & 0xFFFF0000u), emb1);
            }
            float2 st = make_float2(emb0, emb1);
            *reinterpret_cast<float2*>(outE + (size_t)un * E + 2 * j) = st;
        }
    }
}

extern "C" void kernel_launch(void* const* d_in, const int* in_sizes, int n_in,
                              void* d_out, int out_size, void* d_ws, size_t ws_size,
                              hipStream_t stream) {
    const int*   nodes = (const int*)d_in[0];
    const float* nfeat = (const float*)d_in[1];
    const int*   nidx  = (const int*)d_in[2];
    const float* uwt   = (const float*)d_in[3];
    const float* iwt   = (const float*)d_in[4];
    const float* uW    = (const float*)d_in[5];
    const float* ub    = (const float*)d_in[6];
    const float* iW    = (const float*)d_in[7];
    const float* ib    = (const float*)d_in[8];
    const float* aW1   = (const float*)d_in[9];
    const float* ab1   = (const float*)d_in[10];
    const float* aW2   = (const float*)d_in[11];
    const float* ab2   = (const float*)d_in[12];
    const float* aW3   = (const float*)d_in[13];
    // d_in[14] = ab3: softmax-shift-invariant, unused

    float* out_nf  = (float*)d_out;
    float* out_emb = out_nf + (size_t)N_NODES * E;

    char* ws = (char*)d_ws;
    __hip_bfloat16* comb  = (__hip_bfloat16*)(ws);
    __hip_bfloat16* qatt  = (__hip_bfloat16*)(ws + 51200000);
    int*            winner = (int*)(ws + 64000000);
    float*          Wp     = (float*)(ws + 64800000);
    float*          bp     = (float*)(ws + 64832768);
    bf16x8*         B2img  = (bf16x8*)(ws + 64833024);
    float*          bwimg  = (float*)(ws + 64841216);

    hipMemsetAsync(winner, 0xFF, (size_t)N_USERS * sizeof(int), stream);
    hipMemsetAsync(out_emb, 0, (size_t)N_USERS * E * sizeof(float), stream);

    k_fuse<<<34, 256, 0, stream>>>(iW, aW1, ib, ab1, aW2, ab2, aW3,
                                   Wp, bp, B2img, bwimg);
    k_item<<<1024, 256, 0, stream>>>(iwt, iW, ib, Wp, bp, comb);
    k_node1<<<512, 256, 0, stream>>>(nodes, uwt, uW, ub, out_nf, winner);
    k_node2<<<512, 256, 0, stream>>>(out_nf, nfeat, aW1, qatt);
    k_att<<<N_NODES / 32, 256, 0, stream>>>(nodes, nidx, comb, qatt,
                                            B2img, bwimg, winner, out_emb);
}